// Round 1
// baseline (15949.486 us; speedup 1.0000x reference)
//
#include <hip/hip_runtime.h>

// ReLU RNN forward on MI355X (gfx950), bf16 MFMA pipeline.
//
// Stage 1: xih = x @ W_ih^T + b_ih          -> written into hs region of d_out
// Stage 2: for t: hs[:,t,:] = relu(xih_t + hs[:,t-1,:] @ W_hh^T + b_hh)
//          (per-step kernel launches; reads fp32 h from d_out, converts on the fly)
// Stage 3: ys = relu(hs @ W_ho^T + b_ho)
//
// d_ws layout: [W_ih bf16 | W_hh bf16 | W_ho bf16]  (12.6 MB total)

#define DEVI static __device__ __forceinline__

namespace {

constexpr int Bdim = 64, Tdim = 512, Idim = 512, Hdim = 2048, Odim = 512;

using bf16x8 = __attribute__((ext_vector_type(8))) short;
using f32x4  = __attribute__((ext_vector_type(4))) float;

DEVI unsigned short f2bf(float f) {
    // round-to-nearest-even fp32 -> bf16 (values are finite; no NaN handling)
    unsigned int u = __builtin_bit_cast(unsigned int, f);
    u += 0x7fffu + ((u >> 16) & 1u);
    return (unsigned short)(u >> 16);
}

__global__ void cvt_f32_to_bf16(const float* __restrict__ src,
                                unsigned short* __restrict__ dst, int n4) {
    int i = blockIdx.x * blockDim.x + threadIdx.x;
    int stride = gridDim.x * blockDim.x;
    for (; i < n4; i += stride) {
        float4 v = ((const float4*)src)[i];
        ushort4 o;
        o.x = f2bf(v.x); o.y = f2bf(v.y); o.z = f2bf(v.z); o.w = f2bf(v.w);
        ((ushort4*)dst)[i] = o;
    }
}

// C[m][n] = (ADD_C ? C[m][n] : 0) + bias[n] + sum_k A[m][k] * Bw[n][k]
// A: fp32 [.][lda] (converted to bf16 while staging); Bw: bf16 bits [.][ldb].
// BM=64 fixed, BK=64, 256 threads = 4 waves in a 2x2 layout.
// Each wave owns a (32 x BN/2) sub-tile -> acc[2][BN/32] of 16x16 fragments.
// K==0 is legal: skips the matmul (used for t=0 where h_{-1}=0).
template<int BN, bool ADD_C, bool RELU>
__global__ __launch_bounds__(256)
void gemm_bt(const float* __restrict__ A, long lda,
             const unsigned short* __restrict__ Bw, long ldb,
             float* __restrict__ C, long ldc,
             const float* __restrict__ bias, int K)
{
    constexpr int BM  = 64;
    constexpr int BK  = 64;
    constexpr int LDK = BK + 16;   // 80 shorts = 160B row stride: 16B-aligned, ~4-way banks
    constexpr int FN  = BN / 32;   // N-fragments per wave (2 or 1)
    constexpr int RN  = BN / 2;    // wave n-extent

    __shared__ unsigned short As[BM * LDK];
    __shared__ unsigned short Bs[BN * LDK];

    const int tid  = threadIdx.x;
    const int lane = tid & 63;
    const int wave = tid >> 6;
    const int l15  = lane & 15;
    const int lhi  = lane >> 4;
    const int wm   = wave >> 1;    // 0..1
    const int wn   = wave & 1;     // 0..1
    const long m0  = (long)blockIdx.y * BM;
    const long n0  = (long)blockIdx.x * BN;

    f32x4 acc[2][FN];
#pragma unroll
    for (int i = 0; i < 2; ++i)
#pragma unroll
        for (int j = 0; j < FN; ++j)
            acc[i][j] = (f32x4){0.f, 0.f, 0.f, 0.f};

    const int ar = tid >> 2;         // 0..63  (A stage: row)
    const int ak = (tid & 3) * 16;   // 0..48  (A stage: k base, 16 floats/thread)
    const int nIter = K / BK;

    for (int kt = 0; kt < nIter; ++kt) {
        __syncthreads();   // protect LDS from previous iteration's readers
        // ---- stage A tile: fp32 global -> bf16 LDS (16 elems/thread) ----
        {
            const float* ap = A + (m0 + ar) * lda + (long)kt * BK + ak;
            float4 v0 = *(const float4*)(ap + 0);
            float4 v1 = *(const float4*)(ap + 4);
            float4 v2 = *(const float4*)(ap + 8);
            float4 v3 = *(const float4*)(ap + 12);
            union { unsigned short s[8]; bf16x8 v; } p0, p1;
            p0.s[0]=f2bf(v0.x); p0.s[1]=f2bf(v0.y); p0.s[2]=f2bf(v0.z); p0.s[3]=f2bf(v0.w);
            p0.s[4]=f2bf(v1.x); p0.s[5]=f2bf(v1.y); p0.s[6]=f2bf(v1.z); p0.s[7]=f2bf(v1.w);
            p1.s[0]=f2bf(v2.x); p1.s[1]=f2bf(v2.y); p1.s[2]=f2bf(v2.z); p1.s[3]=f2bf(v2.w);
            p1.s[4]=f2bf(v3.x); p1.s[5]=f2bf(v3.y); p1.s[6]=f2bf(v3.z); p1.s[7]=f2bf(v3.w);
            *(bf16x8*)&As[ar * LDK + ak]     = p0.v;
            *(bf16x8*)&As[ar * LDK + ak + 8] = p1.v;
        }
        // ---- stage B tile: bf16 global -> LDS ----
        if constexpr (BN == 64) {
            const int br = tid >> 2, bk = (tid & 3) * 16;   // 16 bf16/thread
            const unsigned short* bp = Bw + (n0 + br) * ldb + (long)kt * BK + bk;
            uint4 w0 = *(const uint4*)(bp + 0);
            uint4 w1 = *(const uint4*)(bp + 8);
            *(uint4*)&Bs[br * LDK + bk]     = w0;
            *(uint4*)&Bs[br * LDK + bk + 8] = w1;
        } else {  // BN == 32
            const int br = tid >> 3, bk = (tid & 7) * 8;    // 8 bf16/thread
            const unsigned short* bp = Bw + (n0 + br) * ldb + (long)kt * BK + bk;
            uint4 w0 = *(const uint4*)(bp);
            *(uint4*)&Bs[br * LDK + bk] = w0;
        }
        __syncthreads();
        // ---- MFMA over the two K=32 sub-chunks ----
#pragma unroll
        for (int ks = 0; ks < 2; ++ks) {
            // A frag: lane holds A[row = l15][k = ks*32 + lhi*8 + j], j=0..7
            bf16x8 a0 = *(const bf16x8*)&As[(wm * 32 +      l15) * LDK + ks * 32 + lhi * 8];
            bf16x8 a1 = *(const bf16x8*)&As[(wm * 32 + 16 + l15) * LDK + ks * 32 + lhi * 8];
#pragma unroll
            for (int j = 0; j < FN; ++j) {
                bf16x8 bj = *(const bf16x8*)&Bs[(wn * RN + j * 16 + l15) * LDK + ks * 32 + lhi * 8];
                acc[0][j] = __builtin_amdgcn_mfma_f32_16x16x32_bf16(a0, bj, acc[0][j], 0, 0, 0);
                acc[1][j] = __builtin_amdgcn_mfma_f32_16x16x32_bf16(a1, bj, acc[1][j], 0, 0, 0);
            }
        }
    }

    // ---- epilogue: C/D layout col = lane&15, row = (lane>>4)*4 + reg ----
#pragma unroll
    for (int i = 0; i < 2; ++i) {
#pragma unroll
        for (int j = 0; j < FN; ++j) {
            const long row = m0 + wm * 32 + i * 16 + lhi * 4;
            const long col = n0 + wn * RN + j * 16 + l15;
            const float bv = bias[col];
#pragma unroll
            for (int r = 0; r < 4; ++r) {
                const long off = (row + r) * ldc + col;
                float v = acc[i][j][r] + bv;
                if (ADD_C) v += C[off];     // xih term (written by stage 1)
                if (RELU)  v = fmaxf(v, 0.f);
                C[off] = v;
            }
        }
    }
}

}  // namespace

extern "C" void kernel_launch(void* const* d_in, const int* in_sizes, int n_in,
                              void* d_out, int out_size, void* d_ws, size_t ws_size,
                              hipStream_t stream)
{
    const float* x    = (const float*)d_in[0];
    const float* W_ih = (const float*)d_in[1];
    const float* b_ih = (const float*)d_in[2];
    const float* W_hh = (const float*)d_in[3];
    const float* b_hh = (const float*)d_in[4];
    const float* W_ho = (const float*)d_in[5];
    const float* b_ho = (const float*)d_in[6];

    float* hs = (float*)d_out;                        // [B][T][H] fp32
    float* ys = hs + (long)Bdim * Tdim * Hdim;        // [B][T][O] fp32

    unsigned short* Wih_b = (unsigned short*)d_ws;             // H*I bf16
    unsigned short* Whh_b = Wih_b + (long)Hdim * Idim;         // H*H bf16
    unsigned short* Who_b = Whh_b + (long)Hdim * Hdim;         // O*H bf16

    // weight conversions (re-run every call: deterministic, inputs unchanged)
    cvt_f32_to_bf16<<<256, 256, 0, stream>>>(W_ih, Wih_b, Hdim * Idim / 4);
    cvt_f32_to_bf16<<<512, 256, 0, stream>>>(W_hh, Whh_b, Hdim * Hdim / 4);
    cvt_f32_to_bf16<<<256, 256, 0, stream>>>(W_ho, Who_b, Odim * Hdim / 4);

    // Stage 1: xih -> hs region. M = B*T = 32768, N = H, K = I.
    gemm_bt<64, false, false><<<dim3(Hdim / 64, (Bdim * Tdim) / 64), 256, 0, stream>>>(
        x, Idim, Wih_b, Idim, hs, Hdim, b_ih, Idim);

    // Stage 2: recurrence. Per step: M = B = 64 (rows stride T*H), N = H, K = H.
    // t = 0 passes K = 0 -> acc stays zero -> h_0 = relu(xih_0 + b_hh).
    for (int t = 0; t < Tdim; ++t) {
        const float* Ap = (t == 0) ? hs : (hs + (long)(t - 1) * Hdim);
        gemm_bt<32, true, true><<<dim3(Hdim / 32, 1), 256, 0, stream>>>(
            Ap, (long)Tdim * Hdim, Whh_b, Hdim,
            hs + (long)t * Hdim, (long)Tdim * Hdim, b_hh,
            (t == 0) ? 0 : Hdim);
    }

    // Stage 3: ys = relu(hs @ W_ho^T + b_ho). M = B*T, N = O, K = H.
    gemm_bt<64, false, true><<<dim3(Odim / 64, (Bdim * Tdim) / 64), 256, 0, stream>>>(
        hs, Hdim, Who_b, Hdim, ys, Odim, b_ho, Hdim);
}

// Round 2
// 13115.552 us; speedup vs baseline: 1.2161x; 1.2161x over previous
//
#include <hip/hip_runtime.h>
#include <hip/hip_cooperative_groups.h>

// ReLU RNN forward on MI355X (gfx950), bf16 MFMA pipeline.
//
// Stage 1: xih = x @ W_ih^T + b_ih          -> written into hs region of d_out
// Stage 2: ONE persistent cooperative kernel, 512 steps with grid.sync():
//          h_t = relu(xih_t + h_{t-1} @ W_hh^T + b_hh)
//          W_hh slice resident in LDS (64KB/WG); h ping-pong bf16 buffer.
// Stage 3: ys = relu(hs @ W_ho^T + b_ho)
//
// d_ws layout: [W_ih bf16 | W_hh bf16 | W_ho bf16]; h ping-pong buffer
// aliases the W_ih region (dead after stage 1).

#define DEVI static __device__ __forceinline__

namespace cg = cooperative_groups;

namespace {

constexpr int Bdim = 64, Tdim = 512, Idim = 512, Hdim = 2048, Odim = 512;

using bf16x8 = __attribute__((ext_vector_type(8))) short;
using f32x4  = __attribute__((ext_vector_type(4))) float;

DEVI unsigned short f2bf(float f) {
    unsigned int u = __builtin_bit_cast(unsigned int, f);
    u += 0x7fffu + ((u >> 16) & 1u);
    return (unsigned short)(u >> 16);
}

__global__ void cvt_f32_to_bf16(const float* __restrict__ src,
                                unsigned short* __restrict__ dst, int n4) {
    int i = blockIdx.x * blockDim.x + threadIdx.x;
    int stride = gridDim.x * blockDim.x;
    for (; i < n4; i += stride) {
        float4 v = ((const float4*)src)[i];
        ushort4 o;
        o.x = f2bf(v.x); o.y = f2bf(v.y); o.z = f2bf(v.z); o.w = f2bf(v.w);
        ((ushort4*)dst)[i] = o;
    }
}

// ---------------- big GEMMs (stages 1 and 3), unchanged from round 1 --------
template<int BN, bool ADD_C, bool RELU>
__global__ __launch_bounds__(256)
void gemm_bt(const float* __restrict__ A, long lda,
             const unsigned short* __restrict__ Bw, long ldb,
             float* __restrict__ C, long ldc,
             const float* __restrict__ bias, int K)
{
    constexpr int BM  = 64;
    constexpr int BK  = 64;
    constexpr int LDK = BK + 16;
    constexpr int FN  = BN / 32;
    constexpr int RN  = BN / 2;

    __shared__ unsigned short As[BM * LDK];
    __shared__ unsigned short Bs[BN * LDK];

    const int tid  = threadIdx.x;
    const int lane = tid & 63;
    const int wave = tid >> 6;
    const int l15  = lane & 15;
    const int lhi  = lane >> 4;
    const int wm   = wave >> 1;
    const int wn   = wave & 1;
    const long m0  = (long)blockIdx.y * BM;
    const long n0  = (long)blockIdx.x * BN;

    f32x4 acc[2][FN];
#pragma unroll
    for (int i = 0; i < 2; ++i)
#pragma unroll
        for (int j = 0; j < FN; ++j)
            acc[i][j] = (f32x4){0.f, 0.f, 0.f, 0.f};

    const int ar = tid >> 2;
    const int ak = (tid & 3) * 16;
    const int nIter = K / BK;

    for (int kt = 0; kt < nIter; ++kt) {
        __syncthreads();
        {
            const float* ap = A + (m0 + ar) * lda + (long)kt * BK + ak;
            float4 v0 = *(const float4*)(ap + 0);
            float4 v1 = *(const float4*)(ap + 4);
            float4 v2 = *(const float4*)(ap + 8);
            float4 v3 = *(const float4*)(ap + 12);
            union { unsigned short s[8]; bf16x8 v; } p0, p1;
            p0.s[0]=f2bf(v0.x); p0.s[1]=f2bf(v0.y); p0.s[2]=f2bf(v0.z); p0.s[3]=f2bf(v0.w);
            p0.s[4]=f2bf(v1.x); p0.s[5]=f2bf(v1.y); p0.s[6]=f2bf(v1.z); p0.s[7]=f2bf(v1.w);
            p1.s[0]=f2bf(v2.x); p1.s[1]=f2bf(v2.y); p1.s[2]=f2bf(v2.z); p1.s[3]=f2bf(v2.w);
            p1.s[4]=f2bf(v3.x); p1.s[5]=f2bf(v3.y); p1.s[6]=f2bf(v3.z); p1.s[7]=f2bf(v3.w);
            *(bf16x8*)&As[ar * LDK + ak]     = p0.v;
            *(bf16x8*)&As[ar * LDK + ak + 8] = p1.v;
        }
        if constexpr (BN == 64) {
            const int br = tid >> 2, bk = (tid & 3) * 16;
            const unsigned short* bp = Bw + (n0 + br) * ldb + (long)kt * BK + bk;
            uint4 w0 = *(const uint4*)(bp + 0);
            uint4 w1 = *(const uint4*)(bp + 8);
            *(uint4*)&Bs[br * LDK + bk]     = w0;
            *(uint4*)&Bs[br * LDK + bk + 8] = w1;
        } else {
            const int br = tid >> 3, bk = (tid & 7) * 8;
            const unsigned short* bp = Bw + (n0 + br) * ldb + (long)kt * BK + bk;
            uint4 w0 = *(const uint4*)(bp);
            *(uint4*)&Bs[br * LDK + bk] = w0;
        }
        __syncthreads();
#pragma unroll
        for (int ks = 0; ks < 2; ++ks) {
            bf16x8 a0 = *(const bf16x8*)&As[(wm * 32 +      l15) * LDK + ks * 32 + lhi * 8];
            bf16x8 a1 = *(const bf16x8*)&As[(wm * 32 + 16 + l15) * LDK + ks * 32 + lhi * 8];
#pragma unroll
            for (int j = 0; j < FN; ++j) {
                bf16x8 bj = *(const bf16x8*)&Bs[(wn * RN + j * 16 + l15) * LDK + ks * 32 + lhi * 8];
                acc[0][j] = __builtin_amdgcn_mfma_f32_16x16x32_bf16(a0, bj, acc[0][j], 0, 0, 0);
                acc[1][j] = __builtin_amdgcn_mfma_f32_16x16x32_bf16(a1, bj, acc[1][j], 0, 0, 0);
            }
        }
    }

#pragma unroll
    for (int i = 0; i < 2; ++i) {
#pragma unroll
        for (int j = 0; j < FN; ++j) {
            const long row = m0 + wm * 32 + i * 16 + lhi * 4;
            const long col = n0 + wn * RN + j * 16 + l15;
            const float bv = bias[col];
#pragma unroll
            for (int r = 0; r < 4; ++r) {
                const long off = (row + r) * ldc + col;
                float v = acc[i][j][r] + bv;
                if (ADD_C) v += C[off];
                if (RELU)  v = fmaxf(v, 0.f);
                C[off] = v;
            }
        }
    }
}

// ---------------- persistent recurrence kernel ------------------------------
// 128 WGs x 256 threads (cooperative). WG owns NC=16 output columns; its
// W_hh slice lives in LDS (exactly 64KB) in [k/8][n][k%8] subtile layout so
// the wave's B-fragment ds_read_b128 is a dense, conflict-free 1KB block.
// h ping-pong: bf16 [2][B][H] in ws. One grid.sync() per step.
constexpr int NWG = 128;
constexpr int NC  = Hdim / NWG;   // 16

__global__ __launch_bounds__(256, 1)
void rnn_steps(const unsigned short* __restrict__ Whh,   // [H][H] bf16
               const float* __restrict__ b_hh,
               float* __restrict__ hs,                   // [B][T][H] f32 (xih in, h out)
               unsigned short* __restrict__ hbuf)        // [2][B][H] bf16
{
    __shared__ unsigned short Wl[(Hdim / 8) * NC * 8];   // 65536 bytes

    const int tid  = threadIdx.x;
    const int lane = tid & 63;
    const int wave = tid >> 6;
    const int l15  = lane & 15;
    const int lhi  = lane >> 4;
    const int n0   = blockIdx.x * NC;

    // stage W slice: element (n,k) -> Wl[(k>>3)*NC*8 + n*8 + (k&7)]
    for (int i = tid; i < (Hdim / 8) * NC; i += 256) {
        const int kblk = i >> 4;          // i / NC
        const int n    = i & (NC - 1);
        uint4 w = *(const uint4*)&Whh[(long)(n0 + n) * Hdim + kblk * 8];
        *(uint4*)&Wl[(kblk * NC + n) * 8] = w;
    }

    const float bias    = b_hh[n0 + l15];
    const int   rowbase = wave * 16;                       // this wave's batch rows
    const long  aoff    = (long)(rowbase + l15) * Hdim + lhi * 8;  // A-frag offset (shorts)
    const int   boff    = (lhi * NC + l15) * 8;            // B LDS offset (shorts); +512/kt

    cg::grid_group grid = cg::this_grid();
    __syncthreads();  // Wl ready

    for (int t = 0; t < Tdim; ++t) {
        // xih prefetch for this lane's 4 output rows (independent of matmul)
        const long obase = (long)(rowbase + lhi * 4) * (Tdim * Hdim)
                         + (long)t * Hdim + n0 + l15;
        float xv[4];
#pragma unroll
        for (int r = 0; r < 4; ++r) xv[r] = hs[obase + (long)r * (Tdim * Hdim)];

        f32x4 acc = (f32x4){0.f, 0.f, 0.f, 0.f};
        if (t > 0) {
            const unsigned short* hp = hbuf + ((t - 1) & 1) * (Bdim * Hdim);
            f32x4 a0 = acc, a1 = acc, a2 = acc, a3 = acc;
#pragma unroll 2
            for (int kt = 0; kt < Hdim / 32; kt += 4) {
                bf16x8 A0 = *(const bf16x8*)&hp[aoff + (long)(kt + 0) * 32];
                bf16x8 B0 = *(const bf16x8*)&Wl[boff + (kt + 0) * 512];
                bf16x8 A1 = *(const bf16x8*)&hp[aoff + (long)(kt + 1) * 32];
                bf16x8 B1 = *(const bf16x8*)&Wl[boff + (kt + 1) * 512];
                bf16x8 A2 = *(const bf16x8*)&hp[aoff + (long)(kt + 2) * 32];
                bf16x8 B2 = *(const bf16x8*)&Wl[boff + (kt + 2) * 512];
                bf16x8 A3 = *(const bf16x8*)&hp[aoff + (long)(kt + 3) * 32];
                bf16x8 B3 = *(const bf16x8*)&Wl[boff + (kt + 3) * 512];
                a0 = __builtin_amdgcn_mfma_f32_16x16x32_bf16(A0, B0, a0, 0, 0, 0);
                a1 = __builtin_amdgcn_mfma_f32_16x16x32_bf16(A1, B1, a1, 0, 0, 0);
                a2 = __builtin_amdgcn_mfma_f32_16x16x32_bf16(A2, B2, a2, 0, 0, 0);
                a3 = __builtin_amdgcn_mfma_f32_16x16x32_bf16(A3, B3, a3, 0, 0, 0);
            }
            acc = (a0 + a1) + (a2 + a3);
        }

        unsigned short* hn = hbuf + (t & 1) * (Bdim * Hdim);
#pragma unroll
        for (int r = 0; r < 4; ++r) {
            float v = acc[r] + xv[r] + bias;
            v = fmaxf(v, 0.f);
            hs[obase + (long)r * (Tdim * Hdim)] = v;                  // fp32 output
            hn[(rowbase + lhi * 4 + r) * Hdim + n0 + l15] = f2bf(v);  // bf16 for next step
        }
        grid.sync();
    }
}

}  // namespace

extern "C" void kernel_launch(void* const* d_in, const int* in_sizes, int n_in,
                              void* d_out, int out_size, void* d_ws, size_t ws_size,
                              hipStream_t stream)
{
    const float* x    = (const float*)d_in[0];
    const float* W_ih = (const float*)d_in[1];
    const float* b_ih = (const float*)d_in[2];
    const float* W_hh = (const float*)d_in[3];
    const float* b_hh = (const float*)d_in[4];
    const float* W_ho = (const float*)d_in[5];
    const float* b_ho = (const float*)d_in[6];

    float* hs = (float*)d_out;                        // [B][T][H] fp32
    float* ys = hs + (long)Bdim * Tdim * Hdim;        // [B][T][O] fp32

    unsigned short* Wih_b = (unsigned short*)d_ws;             // H*I bf16
    unsigned short* Whh_b = Wih_b + (long)Hdim * Idim;         // H*H bf16
    unsigned short* Who_b = Whh_b + (long)Hdim * Hdim;         // O*H bf16
    unsigned short* hbuf  = Wih_b;   // [2][B][H] bf16, aliases W_ih (dead after stage 1)

    cvt_f32_to_bf16<<<256, 256, 0, stream>>>(W_ih, Wih_b, Hdim * Idim / 4);
    cvt_f32_to_bf16<<<512, 256, 0, stream>>>(W_hh, Whh_b, Hdim * Hdim / 4);
    cvt_f32_to_bf16<<<256, 256, 0, stream>>>(W_ho, Who_b, Odim * Hdim / 4);

    // Stage 1: xih -> hs region. M = B*T, N = H, K = I.
    gemm_bt<64, false, false><<<dim3(Hdim / 64, (Bdim * Tdim) / 64), 256, 0, stream>>>(
        x, Idim, Wih_b, Idim, hs, Hdim, b_ih, Idim);

    // Stage 2: persistent cooperative recurrence (one launch, 512 grid syncs).
    {
        const unsigned short* whh = Whh_b;
        const float* bhh = b_hh;
        float* hsp = hs;
        unsigned short* hb = hbuf;
        void* args[] = {(void*)&whh, (void*)&bhh, (void*)&hsp, (void*)&hb};
        hipLaunchCooperativeKernel((void*)rnn_steps, dim3(NWG), dim3(256),
                                   args, 0, stream);
    }

    // Stage 3: ys = relu(hs @ W_ho^T + b_ho). M = B*T, N = O, K = H.
    gemm_bt<64, false, true><<<dim3(Odim / 64, (Bdim * Tdim) / 64), 256, 0, stream>>>(
        hs, Hdim, Who_b, Hdim, ys, Odim, b_ho, Hdim);
}

// Round 3
// 9205.732 us; speedup vs baseline: 1.7326x; 1.4247x over previous
//
#include <hip/hip_runtime.h>
#include <hip/hip_cooperative_groups.h>

// ReLU RNN forward on MI355X (gfx950), bf16 MFMA pipeline.
//
// Stage 1: xih = x @ W_ih^T + b_ih          -> written into hs region of d_out
// Stage 2: ONE persistent cooperative kernel, 512 steps. Cross-WG sync is a
//          lagged distributed-flag barrier (per-WG flag + agent-scope
//          release/acquire fences), NOT cg::grid.sync() (which measured
//          ~24 us/step in round 2).
// Stage 3: ys = relu(hs @ W_ho^T + b_ho)
//
// d_ws layout: [W_ih bf16 | W_hh bf16 | W_ho bf16 | flags]; h ping-pong
// buffer aliases the W_ih region (dead after stage 1).

#define DEVI static __device__ __forceinline__

namespace {

constexpr int Bdim = 64, Tdim = 512, Idim = 512, Hdim = 2048, Odim = 512;

using bf16x8 = __attribute__((ext_vector_type(8))) short;
using f32x4  = __attribute__((ext_vector_type(4))) float;

DEVI unsigned short f2bf(float f) {
    unsigned int u = __builtin_bit_cast(unsigned int, f);
    u += 0x7fffu + ((u >> 16) & 1u);
    return (unsigned short)(u >> 16);
}

__global__ void cvt_f32_to_bf16(const float* __restrict__ src,
                                unsigned short* __restrict__ dst, int n4) {
    int i = blockIdx.x * blockDim.x + threadIdx.x;
    int stride = gridDim.x * blockDim.x;
    for (; i < n4; i += stride) {
        float4 v = ((const float4*)src)[i];
        ushort4 o;
        o.x = f2bf(v.x); o.y = f2bf(v.y); o.z = f2bf(v.z); o.w = f2bf(v.w);
        ((ushort4*)dst)[i] = o;
    }
}

// ---------------- big GEMMs (stages 1 and 3) --------------------------------
template<int BN, bool ADD_C, bool RELU>
__global__ __launch_bounds__(256)
void gemm_bt(const float* __restrict__ A, long lda,
             const unsigned short* __restrict__ Bw, long ldb,
             float* __restrict__ C, long ldc,
             const float* __restrict__ bias, int K)
{
    constexpr int BM  = 64;
    constexpr int BK  = 64;
    constexpr int LDK = BK + 16;
    constexpr int FN  = BN / 32;
    constexpr int RN  = BN / 2;

    __shared__ unsigned short As[BM * LDK];
    __shared__ unsigned short Bs[BN * LDK];

    const int tid  = threadIdx.x;
    const int lane = tid & 63;
    const int wave = tid >> 6;
    const int l15  = lane & 15;
    const int lhi  = lane >> 4;
    const int wm   = wave >> 1;
    const int wn   = wave & 1;
    const long m0  = (long)blockIdx.y * BM;
    const long n0  = (long)blockIdx.x * BN;

    f32x4 acc[2][FN];
#pragma unroll
    for (int i = 0; i < 2; ++i)
#pragma unroll
        for (int j = 0; j < FN; ++j)
            acc[i][j] = (f32x4){0.f, 0.f, 0.f, 0.f};

    const int ar = tid >> 2;
    const int ak = (tid & 3) * 16;
    const int nIter = K / BK;

    for (int kt = 0; kt < nIter; ++kt) {
        __syncthreads();
        {
            const float* ap = A + (m0 + ar) * lda + (long)kt * BK + ak;
            float4 v0 = *(const float4*)(ap + 0);
            float4 v1 = *(const float4*)(ap + 4);
            float4 v2 = *(const float4*)(ap + 8);
            float4 v3 = *(const float4*)(ap + 12);
            union { unsigned short s[8]; bf16x8 v; } p0, p1;
            p0.s[0]=f2bf(v0.x); p0.s[1]=f2bf(v0.y); p0.s[2]=f2bf(v0.z); p0.s[3]=f2bf(v0.w);
            p0.s[4]=f2bf(v1.x); p0.s[5]=f2bf(v1.y); p0.s[6]=f2bf(v1.z); p0.s[7]=f2bf(v1.w);
            p1.s[0]=f2bf(v2.x); p1.s[1]=f2bf(v2.y); p1.s[2]=f2bf(v2.z); p1.s[3]=f2bf(v2.w);
            p1.s[4]=f2bf(v3.x); p1.s[5]=f2bf(v3.y); p1.s[6]=f2bf(v3.z); p1.s[7]=f2bf(v3.w);
            *(bf16x8*)&As[ar * LDK + ak]     = p0.v;
            *(bf16x8*)&As[ar * LDK + ak + 8] = p1.v;
        }
        if constexpr (BN == 64) {
            const int br = tid >> 2, bk = (tid & 3) * 16;
            const unsigned short* bp = Bw + (n0 + br) * ldb + (long)kt * BK + bk;
            uint4 w0 = *(const uint4*)(bp + 0);
            uint4 w1 = *(const uint4*)(bp + 8);
            *(uint4*)&Bs[br * LDK + bk]     = w0;
            *(uint4*)&Bs[br * LDK + bk + 8] = w1;
        } else {
            const int br = tid >> 3, bk = (tid & 7) * 8;
            const unsigned short* bp = Bw + (n0 + br) * ldb + (long)kt * BK + bk;
            uint4 w0 = *(const uint4*)(bp);
            *(uint4*)&Bs[br * LDK + bk] = w0;
        }
        __syncthreads();
#pragma unroll
        for (int ks = 0; ks < 2; ++ks) {
            bf16x8 a0 = *(const bf16x8*)&As[(wm * 32 +      l15) * LDK + ks * 32 + lhi * 8];
            bf16x8 a1 = *(const bf16x8*)&As[(wm * 32 + 16 + l15) * LDK + ks * 32 + lhi * 8];
#pragma unroll
            for (int j = 0; j < FN; ++j) {
                bf16x8 bj = *(const bf16x8*)&Bs[(wn * RN + j * 16 + l15) * LDK + ks * 32 + lhi * 8];
                acc[0][j] = __builtin_amdgcn_mfma_f32_16x16x32_bf16(a0, bj, acc[0][j], 0, 0, 0);
                acc[1][j] = __builtin_amdgcn_mfma_f32_16x16x32_bf16(a1, bj, acc[1][j], 0, 0, 0);
            }
        }
    }

#pragma unroll
    for (int i = 0; i < 2; ++i) {
#pragma unroll
        for (int j = 0; j < FN; ++j) {
            const long row = m0 + wm * 32 + i * 16 + lhi * 4;
            const long col = n0 + wn * RN + j * 16 + l15;
            const float bv = bias[col];
#pragma unroll
            for (int r = 0; r < 4; ++r) {
                const long off = (row + r) * ldc + col;
                float v = acc[i][j][r] + bv;
                if (ADD_C) v += C[off];
                if (RELU)  v = fmaxf(v, 0.f);
                C[off] = v;
            }
        }
    }
}

// ---------------- persistent recurrence kernel ------------------------------
// 128 WGs x 256 threads (cooperative launch for co-residency guarantee only;
// grid.sync() is NOT used). WG owns NC=16 output columns; W_hh slice resident
// in LDS (64KB) in [k/8][n][k%8] layout. h ping-pong bf16 [2][B][H] in ws.
//
// Lagged flag barrier: flag[i] = t+1 means "WG i wrote its h_t slice AND has
// finished all reads of h_{t-1}". Before step t (>0), wait all flags >= t:
//   - guarantees h_{t-1} fully written (safe to read buf[(t-1)&1])
//   - guarantees everyone is done reading h_{t-2} (safe to overwrite buf[t&1])
constexpr int NWG   = 128;
constexpr int NC    = Hdim / NWG;   // 16
constexpr int FSTR  = 32;           // flag stride in ints (128B apart)

__global__ __launch_bounds__(256, 1)
void rnn_steps(const unsigned short* __restrict__ Whh,   // [H][H] bf16
               const float* __restrict__ b_hh,
               float* __restrict__ hs,                   // [B][T][H] f32 (xih in, h out)
               unsigned short* __restrict__ hbuf,        // [2][B][H] bf16
               int* __restrict__ flags)                  // [NWG*FSTR], zeroed per call
{
    __shared__ unsigned short Wl[(Hdim / 8) * NC * 8];   // 65536 bytes

    const int tid  = threadIdx.x;
    const int lane = tid & 63;
    const int wave = tid >> 6;
    const int l15  = lane & 15;
    const int lhi  = lane >> 4;
    const int n0   = blockIdx.x * NC;
    const int me   = blockIdx.x;

    // stage W slice: element (n,k) -> Wl[(k>>3)*NC*8 + n*8 + (k&7)]
    for (int i = tid; i < (Hdim / 8) * NC; i += 256) {
        const int kblk = i >> 4;          // i / NC
        const int n    = i & (NC - 1);
        uint4 w = *(const uint4*)&Whh[(long)(n0 + n) * Hdim + kblk * 8];
        *(uint4*)&Wl[(kblk * NC + n) * 8] = w;
    }

    const float bias    = b_hh[n0 + l15];
    const int   rowbase = wave * 16;
    const long  aoff    = (long)(rowbase + l15) * Hdim + lhi * 8;  // A-frag (shorts)
    const int   boff    = (lhi * NC + l15) * 8;                    // B LDS (shorts)

    __syncthreads();  // Wl ready

    for (int t = 0; t < Tdim; ++t) {
        // xih loads for this lane's 4 output rows — issued BEFORE the spin
        // (independent of h; latency hides under the barrier wait).
        const long obase = (long)(rowbase + lhi * 4) * (Tdim * Hdim)
                         + (long)t * Hdim + n0 + l15;
        float xv[4];
#pragma unroll
        for (int r = 0; r < 4; ++r) xv[r] = hs[obase + (long)r * (Tdim * Hdim)];

        f32x4 acc = (f32x4){0.f, 0.f, 0.f, 0.f};
        if (t > 0) {
            // ---- lagged barrier wait: all flags >= t ----
            if (tid < NWG) {
                while (__hip_atomic_load(&flags[tid * FSTR], __ATOMIC_RELAXED,
                                         __HIP_MEMORY_SCOPE_AGENT) < t) {
                    __builtin_amdgcn_s_sleep(1);
                }
            }
            __syncthreads();
            __builtin_amdgcn_fence(__ATOMIC_ACQUIRE, "agent");  // buffer_inv

            const unsigned short* hp = hbuf + ((t - 1) & 1) * (Bdim * Hdim);
            f32x4 a0 = acc, a1 = acc, a2 = acc, a3 = acc;
#pragma unroll 2
            for (int kt = 0; kt < Hdim / 32; kt += 4) {
                bf16x8 A0 = *(const bf16x8*)&hp[aoff + (long)(kt + 0) * 32];
                bf16x8 B0 = *(const bf16x8*)&Wl[boff + (kt + 0) * 512];
                bf16x8 A1 = *(const bf16x8*)&hp[aoff + (long)(kt + 1) * 32];
                bf16x8 B1 = *(const bf16x8*)&Wl[boff + (kt + 1) * 512];
                bf16x8 A2 = *(const bf16x8*)&hp[aoff + (long)(kt + 2) * 32];
                bf16x8 B2 = *(const bf16x8*)&Wl[boff + (kt + 2) * 512];
                bf16x8 A3 = *(const bf16x8*)&hp[aoff + (long)(kt + 3) * 32];
                bf16x8 B3 = *(const bf16x8*)&Wl[boff + (kt + 3) * 512];
                a0 = __builtin_amdgcn_mfma_f32_16x16x32_bf16(A0, B0, a0, 0, 0, 0);
                a1 = __builtin_amdgcn_mfma_f32_16x16x32_bf16(A1, B1, a1, 0, 0, 0);
                a2 = __builtin_amdgcn_mfma_f32_16x16x32_bf16(A2, B2, a2, 0, 0, 0);
                a3 = __builtin_amdgcn_mfma_f32_16x16x32_bf16(A3, B3, a3, 0, 0, 0);
            }
            acc = (a0 + a1) + (a2 + a3);
        }

        unsigned short* hn = hbuf + (t & 1) * (Bdim * Hdim);
#pragma unroll
        for (int r = 0; r < 4; ++r) {
            float v = acc[r] + xv[r] + bias;
            v = fmaxf(v, 0.f);
            hs[obase + (long)r * (Tdim * Hdim)] = v;                  // fp32 output
            hn[(rowbase + lhi * 4 + r) * Hdim + n0 + l15] = f2bf(v);  // bf16 next step
        }

        // ---- publish: all WG stores drained at the barrier, then one
        // release fence (waitcnt + buffer_wbl2) + relaxed flag store ----
        __syncthreads();
        if (tid == 0) {
            __builtin_amdgcn_fence(__ATOMIC_RELEASE, "agent");
            __hip_atomic_store(&flags[me * FSTR], t + 1, __ATOMIC_RELAXED,
                               __HIP_MEMORY_SCOPE_AGENT);
        }
    }
}

}  // namespace

extern "C" void kernel_launch(void* const* d_in, const int* in_sizes, int n_in,
                              void* d_out, int out_size, void* d_ws, size_t ws_size,
                              hipStream_t stream)
{
    const float* x    = (const float*)d_in[0];
    const float* W_ih = (const float*)d_in[1];
    const float* b_ih = (const float*)d_in[2];
    const float* W_hh = (const float*)d_in[3];
    const float* b_hh = (const float*)d_in[4];
    const float* W_ho = (const float*)d_in[5];
    const float* b_ho = (const float*)d_in[6];

    float* hs = (float*)d_out;                        // [B][T][H] fp32
    float* ys = hs + (long)Bdim * Tdim * Hdim;        // [B][T][O] fp32

    unsigned short* Wih_b = (unsigned short*)d_ws;             // H*I bf16
    unsigned short* Whh_b = Wih_b + (long)Hdim * Idim;         // H*H bf16
    unsigned short* Who_b = Whh_b + (long)Hdim * Hdim;         // O*H bf16
    int* flags = (int*)(Who_b + (long)Odim * Hdim);            // NWG*FSTR ints
    unsigned short* hbuf  = Wih_b;   // [2][B][H] bf16, aliases W_ih (dead after stage 1)

    cvt_f32_to_bf16<<<256, 256, 0, stream>>>(W_ih, Wih_b, Hdim * Idim / 4);
    cvt_f32_to_bf16<<<512, 256, 0, stream>>>(W_hh, Whh_b, Hdim * Hdim / 4);
    cvt_f32_to_bf16<<<256, 256, 0, stream>>>(W_ho, Who_b, Odim * Hdim / 4);

    // zero the barrier flags (stream-ordered, graph-capture-safe)
    hipMemsetAsync(flags, 0, NWG * FSTR * sizeof(int), stream);

    // Stage 1: xih -> hs region. M = B*T, N = H, K = I.
    gemm_bt<64, false, false><<<dim3(Hdim / 64, (Bdim * Tdim) / 64), 256, 0, stream>>>(
        x, Idim, Wih_b, Idim, hs, Hdim, b_ih, Idim);

    // Stage 2: persistent cooperative recurrence (one launch, flag barriers).
    {
        const unsigned short* whh = Whh_b;
        const float* bhh = b_hh;
        float* hsp = hs;
        unsigned short* hb = hbuf;
        int* fl = flags;
        void* args[] = {(void*)&whh, (void*)&bhh, (void*)&hsp, (void*)&hb, (void*)&fl};
        hipLaunchCooperativeKernel((void*)rnn_steps, dim3(NWG), dim3(256),
                                   args, 0, stream);
    }

    // Stage 3: ys = relu(hs @ W_ho^T + b_ho). M = B*T, N = O, K = H.
    gemm_bt<64, false, true><<<dim3(Odim / 64, (Bdim * Tdim) / 64), 256, 0, stream>>>(
        hs, Hdim, Who_b, Hdim, ys, Odim, b_ho, Hdim);
}

// Round 5
// 5151.773 us; speedup vs baseline: 3.0959x; 1.7869x over previous
//
#include <hip/hip_runtime.h>

// ReLU RNN forward on MI355X (gfx950), bf16 MFMA pipeline.
//
// Stage 1: xih = x @ W_ih^T + b_ih          -> written into hs region of d_out
// Stage 2: ONE persistent cooperative kernel, 512 steps. Cross-WG sync is a
//          lagged distributed-flag barrier (no grid.sync, no agent fences).
//          h data path:
//            stores: compiler-generated relaxed AGENT atomic u32 stores
//                    (same op class as the flag stores, proven visible
//                    cross-XCD in rounds 3/4), bf16 pairs packed via shfl.
//            loads:  asm global_load_dwordx4 sc0 sc1 (system-scope, bypasses
//                    the non-coherent L2) in a counted-vmcnt pipeline,
//                    ring of 2 groups (64 VGPRs), vmcnt(8) steady state.
//          ordering: s_waitcnt vmcnt(0) + __syncthreads() before flag store.
// Stage 3: ys = relu(hs @ W_ho^T + b_ho)
//
// d_ws layout: [W_ih bf16 | W_hh bf16 | W_ho bf16 | flags]; h ping-pong
// buffer aliases the W_ih region (dead after stage 1).

#define DEVI static __device__ __forceinline__

namespace {

constexpr int Bdim = 64, Tdim = 512, Idim = 512, Hdim = 2048, Odim = 512;

using bf16x8 = __attribute__((ext_vector_type(8))) short;
using f32x4  = __attribute__((ext_vector_type(4))) float;

DEVI unsigned short f2bf(float f) {
    unsigned int u = __builtin_bit_cast(unsigned int, f);
    u += 0x7fffu + ((u >> 16) & 1u);
    return (unsigned short)(u >> 16);
}

__global__ void cvt_f32_to_bf16(const float* __restrict__ src,
                                unsigned short* __restrict__ dst, int n4) {
    int i = blockIdx.x * blockDim.x + threadIdx.x;
    int stride = gridDim.x * blockDim.x;
    for (; i < n4; i += stride) {
        float4 v = ((const float4*)src)[i];
        ushort4 o;
        o.x = f2bf(v.x); o.y = f2bf(v.y); o.z = f2bf(v.z); o.w = f2bf(v.w);
        ((ushort4*)dst)[i] = o;
    }
}

// ---------------- big GEMMs (stages 1 and 3) --------------------------------
template<int BN, bool ADD_C, bool RELU>
__global__ __launch_bounds__(256)
void gemm_bt(const float* __restrict__ A, long lda,
             const unsigned short* __restrict__ Bw, long ldb,
             float* __restrict__ C, long ldc,
             const float* __restrict__ bias, int K)
{
    constexpr int BM  = 64;
    constexpr int BK  = 64;
    constexpr int LDK = BK + 16;
    constexpr int FN  = BN / 32;
    constexpr int RN  = BN / 2;

    __shared__ unsigned short As[BM * LDK];
    __shared__ unsigned short Bs[BN * LDK];

    const int tid  = threadIdx.x;
    const int lane = tid & 63;
    const int wave = tid >> 6;
    const int l15  = lane & 15;
    const int lhi  = lane >> 4;
    const int wm   = wave >> 1;
    const int wn   = wave & 1;
    const long m0  = (long)blockIdx.y * BM;
    const long n0  = (long)blockIdx.x * BN;

    f32x4 acc[2][FN];
#pragma unroll
    for (int i = 0; i < 2; ++i)
#pragma unroll
        for (int j = 0; j < FN; ++j)
            acc[i][j] = (f32x4){0.f, 0.f, 0.f, 0.f};

    const int ar = tid >> 2;
    const int ak = (tid & 3) * 16;
    const int nIter = K / BK;

    for (int kt = 0; kt < nIter; ++kt) {
        __syncthreads();
        {
            const float* ap = A + (m0 + ar) * lda + (long)kt * BK + ak;
            float4 v0 = *(const float4*)(ap + 0);
            float4 v1 = *(const float4*)(ap + 4);
            float4 v2 = *(const float4*)(ap + 8);
            float4 v3 = *(const float4*)(ap + 12);
            union { unsigned short s[8]; bf16x8 v; } p0, p1;
            p0.s[0]=f2bf(v0.x); p0.s[1]=f2bf(v0.y); p0.s[2]=f2bf(v0.z); p0.s[3]=f2bf(v0.w);
            p0.s[4]=f2bf(v1.x); p0.s[5]=f2bf(v1.y); p0.s[6]=f2bf(v1.z); p0.s[7]=f2bf(v1.w);
            p1.s[0]=f2bf(v2.x); p1.s[1]=f2bf(v2.y); p1.s[2]=f2bf(v2.z); p1.s[3]=f2bf(v2.w);
            p1.s[4]=f2bf(v3.x); p1.s[5]=f2bf(v3.y); p1.s[6]=f2bf(v3.z); p1.s[7]=f2bf(v3.w);
            *(bf16x8*)&As[ar * LDK + ak]     = p0.v;
            *(bf16x8*)&As[ar * LDK + ak + 8] = p1.v;
        }
        if constexpr (BN == 64) {
            const int br = tid >> 2, bk = (tid & 3) * 16;
            const unsigned short* bp = Bw + (n0 + br) * ldb + (long)kt * BK + bk;
            uint4 w0 = *(const uint4*)(bp + 0);
            uint4 w1 = *(const uint4*)(bp + 8);
            *(uint4*)&Bs[br * LDK + bk]     = w0;
            *(uint4*)&Bs[br * LDK + bk + 8] = w1;
        } else {
            const int br = tid >> 3, bk = (tid & 7) * 8;
            const unsigned short* bp = Bw + (n0 + br) * ldb + (long)kt * BK + bk;
            uint4 w0 = *(const uint4*)(bp);
            *(uint4*)&Bs[br * LDK + bk] = w0;
        }
        __syncthreads();
#pragma unroll
        for (int ks = 0; ks < 2; ++ks) {
            bf16x8 a0 = *(const bf16x8*)&As[(wm * 32 +      l15) * LDK + ks * 32 + lhi * 8];
            bf16x8 a1 = *(const bf16x8*)&As[(wm * 32 + 16 + l15) * LDK + ks * 32 + lhi * 8];
#pragma unroll
            for (int j = 0; j < FN; ++j) {
                bf16x8 bj = *(const bf16x8*)&Bs[(wn * RN + j * 16 + l15) * LDK + ks * 32 + lhi * 8];
                acc[0][j] = __builtin_amdgcn_mfma_f32_16x16x32_bf16(a0, bj, acc[0][j], 0, 0, 0);
                acc[1][j] = __builtin_amdgcn_mfma_f32_16x16x32_bf16(a1, bj, acc[1][j], 0, 0, 0);
            }
        }
    }

#pragma unroll
    for (int i = 0; i < 2; ++i) {
#pragma unroll
        for (int j = 0; j < FN; ++j) {
            const long row = m0 + wm * 32 + i * 16 + lhi * 4;
            const long col = n0 + wn * RN + j * 16 + l15;
            const float bv = bias[col];
#pragma unroll
            for (int r = 0; r < 4; ++r) {
                const long off = (row + r) * ldc + col;
                float v = acc[i][j][r] + bv;
                if (ADD_C) v += C[off];
                if (RELU)  v = fmaxf(v, 0.f);
                C[off] = v;
            }
        }
    }
}

// ---------------- persistent recurrence kernel ------------------------------
constexpr int NWG   = 128;
constexpr int NC    = Hdim / NWG;   // 16
constexpr int FSTR  = 32;           // flag stride in ints (128B apart)

// issue 8 system-scope (sc0 sc1: L2-bypassing) 16B loads; completion tracked
// MANUALLY via s_waitcnt vmcnt(N). Early-clobber outputs: dest must not
// overlap the address register pair.
DEVI void issue8(const unsigned short* p, bf16x8* d) {
    asm volatile("global_load_dwordx4 %0, %1, off sc0 sc1"            : "=&v"(d[0]) : "v"(p));
    asm volatile("global_load_dwordx4 %0, %1, off offset:64 sc0 sc1"  : "=&v"(d[1]) : "v"(p));
    asm volatile("global_load_dwordx4 %0, %1, off offset:128 sc0 sc1" : "=&v"(d[2]) : "v"(p));
    asm volatile("global_load_dwordx4 %0, %1, off offset:192 sc0 sc1" : "=&v"(d[3]) : "v"(p));
    asm volatile("global_load_dwordx4 %0, %1, off offset:256 sc0 sc1" : "=&v"(d[4]) : "v"(p));
    asm volatile("global_load_dwordx4 %0, %1, off offset:320 sc0 sc1" : "=&v"(d[5]) : "v"(p));
    asm volatile("global_load_dwordx4 %0, %1, off offset:384 sc0 sc1" : "=&v"(d[6]) : "v"(p));
    asm volatile("global_load_dwordx4 %0, %1, off offset:448 sc0 sc1" : "=&v"(d[7]) : "v"(p));
}

// One K-group: read B frags (LDS, compiler-tracked lgkmcnt), counted vmcnt
// wait for the A group in SLOT, 8 MFMAs, then refill SLOT with group RF.
// Count audit (ring of 2, 4 stray xv loads max): at group g's wait(8),
// completed >= 12+8(g+1) >= position of group g's last load. Never 0 mid-loop.
#define RNN_GROUP(G, SLOT, NW, RF)                                                \
    do {                                                                          \
        bf16x8 Bv[8];                                                             \
        _Pragma("unroll")                                                         \
        for (int j = 0; j < 8; ++j)                                               \
            Bv[j] = *(const bf16x8*)&Wl[boff + ((G) * 8 + j) * 512];              \
        asm volatile("s_waitcnt vmcnt(" #NW ")" ::: "memory");                    \
        __builtin_amdgcn_sched_barrier(0);                                        \
        a0 = __builtin_amdgcn_mfma_f32_16x16x32_bf16(SLOT[0], Bv[0], a0, 0, 0, 0);\
        a1 = __builtin_amdgcn_mfma_f32_16x16x32_bf16(SLOT[1], Bv[1], a1, 0, 0, 0);\
        a2 = __builtin_amdgcn_mfma_f32_16x16x32_bf16(SLOT[2], Bv[2], a2, 0, 0, 0);\
        a3 = __builtin_amdgcn_mfma_f32_16x16x32_bf16(SLOT[3], Bv[3], a3, 0, 0, 0);\
        a0 = __builtin_amdgcn_mfma_f32_16x16x32_bf16(SLOT[4], Bv[4], a0, 0, 0, 0);\
        a1 = __builtin_amdgcn_mfma_f32_16x16x32_bf16(SLOT[5], Bv[5], a1, 0, 0, 0);\
        a2 = __builtin_amdgcn_mfma_f32_16x16x32_bf16(SLOT[6], Bv[6], a2, 0, 0, 0);\
        a3 = __builtin_amdgcn_mfma_f32_16x16x32_bf16(SLOT[7], Bv[7], a3, 0, 0, 0);\
        if ((RF) >= 0) issue8(pA + (RF) * 256, SLOT);                             \
    } while (0)

__global__ __launch_bounds__(256, 1)
void rnn_steps(const unsigned short* __restrict__ Whh,   // [H][H] bf16
               const float* __restrict__ b_hh,
               float* __restrict__ hs,                   // [B][T][H] f32 (xih in, h out)
               unsigned short* __restrict__ hbuf,        // [2][B][H] bf16
               int* __restrict__ flags)                  // [NWG*FSTR], zeroed per call
{
    __shared__ unsigned short Wl[(Hdim / 8) * NC * 8];   // 65536 bytes

    const int tid  = threadIdx.x;
    const int lane = tid & 63;
    const int wave = tid >> 6;
    const int l15  = lane & 15;
    const int lhi  = lane >> 4;
    const int n0   = blockIdx.x * NC;
    const int me   = blockIdx.x;

    // stage W slice: element (n,k) -> Wl[(k>>3)*NC*8 + n*8 + (k&7)]
    for (int i = tid; i < (Hdim / 8) * NC; i += 256) {
        const int kblk = i >> 4;          // i / NC
        const int n    = i & (NC - 1);
        uint4 w = *(const uint4*)&Whh[(long)(n0 + n) * Hdim + kblk * 8];
        *(uint4*)&Wl[(kblk * NC + n) * 8] = w;
    }

    const float bias    = b_hh[n0 + l15];
    const int   rowbase = wave * 16;
    const long  aoff    = (long)(rowbase + l15) * Hdim + lhi * 8;  // A-frag (shorts)
    const int   boff    = (lhi * NC + l15) * 8;                    // B LDS (shorts)

    __syncthreads();  // Wl ready

    for (int t = 0; t < Tdim; ++t) {
        // xih loads (normal cached; WG-private addresses) — issued before the
        // spin so their latency hides under the barrier wait.
        const long obase = (long)(rowbase + lhi * 4) * (Tdim * Hdim)
                         + (long)t * Hdim + n0 + l15;
        float xv[4];
#pragma unroll
        for (int r = 0; r < 4; ++r) xv[r] = hs[obase + (long)r * (Tdim * Hdim)];

        f32x4 a0 = (f32x4){0.f, 0.f, 0.f, 0.f};
        f32x4 a1 = a0, a2 = a0, a3 = a0;

        if (t > 0) {
            // ---- lagged barrier wait: all flags >= t (sc1 polls, no fence) ----
            if (tid < NWG) {
                while (__hip_atomic_load(&flags[tid * FSTR], __ATOMIC_RELAXED,
                                         __HIP_MEMORY_SCOPE_AGENT) < t) {
                    __builtin_amdgcn_s_sleep(1);
                }
            }
            __syncthreads();
            __builtin_amdgcn_sched_barrier(0);   // nothing crosses the barrier

            // ---- counted-vmcnt A pipeline over h_{t-1} (ring of 2 groups) ----
            const unsigned short* pA =
                hbuf + ((t - 1) & 1) * (Bdim * Hdim) + aoff;
            bf16x8 A0[8], A1[8];
            issue8(pA + 0 * 256, A0);
            issue8(pA + 1 * 256, A1);
            RNN_GROUP(0, A0, 8, 2);
            RNN_GROUP(1, A1, 8, 3);
            RNN_GROUP(2, A0, 8, 4);
            RNN_GROUP(3, A1, 8, 5);
            RNN_GROUP(4, A0, 8, 6);
            RNN_GROUP(5, A1, 8, 7);
            RNN_GROUP(6, A0, 8, -1);
            RNN_GROUP(7, A1, 0, -1);
        }

        const f32x4 acc = (a0 + a1) + (a2 + a3);
        unsigned short* hn = hbuf + (t & 1) * (Bdim * Hdim);
        float vv[4];
#pragma unroll
        for (int r = 0; r < 4; ++r) {
            vv[r] = fmaxf(acc[r] + xv[r] + bias, 0.f);
            hs[obase + (long)r * (Tdim * Hdim)] = vv[r];   // fp32 output (cached)
        }
        // pack bf16 column pairs via shfl and store as relaxed AGENT atomic u32
        // (the op class proven to propagate cross-XCD: same as the flags).
#pragma unroll
        for (int r = 0; r < 4; ++r) {
            float other = __shfl_xor(vv[r], 1);
            unsigned int pack = (unsigned int)f2bf(vv[r])
                              | ((unsigned int)f2bf(other) << 16);
            if ((l15 & 1) == 0) {
                unsigned int* wp = (unsigned int*)
                    (hn + (long)(rowbase + lhi * 4 + r) * Hdim + n0 + l15);
                __hip_atomic_store(wp, pack, __ATOMIC_RELAXED,
                                   __HIP_MEMORY_SCOPE_AGENT);
            }
        }

        // ---- publish: drain all vm ops (loads + atomic stores), then flag ----
        asm volatile("s_waitcnt vmcnt(0)" ::: "memory");
        __syncthreads();
        if (tid == 0) {
            __hip_atomic_store(&flags[me * FSTR], t + 1, __ATOMIC_RELAXED,
                               __HIP_MEMORY_SCOPE_AGENT);
        }
    }
}

}  // namespace

extern "C" void kernel_launch(void* const* d_in, const int* in_sizes, int n_in,
                              void* d_out, int out_size, void* d_ws, size_t ws_size,
                              hipStream_t stream)
{
    const float* x    = (const float*)d_in[0];
    const float* W_ih = (const float*)d_in[1];
    const float* b_ih = (const float*)d_in[2];
    const float* W_hh = (const float*)d_in[3];
    const float* b_hh = (const float*)d_in[4];
    const float* W_ho = (const float*)d_in[5];
    const float* b_ho = (const float*)d_in[6];

    float* hs = (float*)d_out;                        // [B][T][H] fp32
    float* ys = hs + (long)Bdim * Tdim * Hdim;        // [B][T][O] fp32

    unsigned short* Wih_b = (unsigned short*)d_ws;             // H*I bf16
    unsigned short* Whh_b = Wih_b + (long)Hdim * Idim;         // H*H bf16
    unsigned short* Who_b = Whh_b + (long)Hdim * Hdim;         // O*H bf16
    int* flags = (int*)(Who_b + (long)Odim * Hdim);            // NWG*FSTR ints
    unsigned short* hbuf  = Wih_b;   // [2][B][H] bf16, aliases W_ih (dead after stage 1)

    cvt_f32_to_bf16<<<256, 256, 0, stream>>>(W_ih, Wih_b, Hdim * Idim / 4);
    cvt_f32_to_bf16<<<512, 256, 0, stream>>>(W_hh, Whh_b, Hdim * Hdim / 4);
    cvt_f32_to_bf16<<<256, 256, 0, stream>>>(W_ho, Who_b, Odim * Hdim / 4);

    // zero the barrier flags (stream-ordered, graph-capture-safe)
    hipMemsetAsync(flags, 0, NWG * FSTR * sizeof(int), stream);

    // Stage 1: xih -> hs region. M = B*T, N = H, K = I.
    gemm_bt<64, false, false><<<dim3(Hdim / 64, (Bdim * Tdim) / 64), 256, 0, stream>>>(
        x, Idim, Wih_b, Idim, hs, Hdim, b_ih, Idim);

    // Stage 2: persistent cooperative recurrence (one launch, flag barriers).
    {
        const unsigned short* whh = Whh_b;
        const float* bhh = b_hh;
        float* hsp = hs;
        unsigned short* hb = hbuf;
        int* fl = flags;
        void* args[] = {(void*)&whh, (void*)&bhh, (void*)&hsp, (void*)&hb, (void*)&fl};
        hipLaunchCooperativeKernel((void*)rnn_steps, dim3(NWG), dim3(256),
                                   args, 0, stream);
    }

    // Stage 3: ys = relu(hs @ W_ho^T + b_ho). M = B*T, N = O, K = H.
    gemm_bt<64, false, true><<<dim3(Odim / 64, (Bdim * Tdim) / 64), 256, 0, stream>>>(
        hs, Hdim, Who_b, Hdim, ys, Odim, b_ho, Hdim);
}